// Round 11
// baseline (181.793 us; speedup 1.0000x reference)
//
#include <hip/hip_runtime.h>
#include <hip/hip_bf16.h>

#define BB   8
#define CIN  512
#define COUT 512
#define ZD   512
#define HH   64
#define WW   64

#define MOD_SCALE  0.04419417382415922f    // 1/sqrt(512)
#define CONV_SCALE 0.014731391274719742f   // 1/sqrt(512*9)

typedef __bf16 bf16x8 __attribute__((ext_vector_type(8)));
typedef float  f32x4  __attribute__((ext_vector_type(4)));
typedef float  f32x16 __attribute__((ext_vector_type(16)));

static __device__ __forceinline__ unsigned short f32_to_bf16_rne(float f) {
    unsigned int u = __float_as_uint(f);
    u = (u + 0x7FFFu + ((u >> 16) & 1u)) >> 16;
    return (unsigned short)u;
}

// ---------------- K0: sconv[b][i] = (style[b]·mod_w[i]*MOD_SCALE + mod_b[i]) * CONV_SCALE
__global__ void k_style(const float* __restrict__ style, const float* __restrict__ mod_w,
                        const float* __restrict__ mod_b, float* __restrict__ sconv) {
    int wid  = blockIdx.x * 4 + (threadIdx.x >> 6);   // 0..4095 = b*512+i
    int lane = threadIdx.x & 63;
    int b = wid >> 9;
    int i = wid & 511;
    const float4* st = (const float4*)(style + (size_t)b * ZD);
    const float4* mw = (const float4*)(mod_w + (size_t)i * ZD);
    float4 a0 = st[lane],      b0 = mw[lane];
    float4 a1 = st[lane + 64], b1 = mw[lane + 64];
    float sum = a0.x*b0.x + a0.y*b0.y + a0.z*b0.z + a0.w*b0.w
              + a1.x*b1.x + a1.y*b1.y + a1.z*b1.z + a1.w*b1.w;
    #pragma unroll
    for (int off = 32; off > 0; off >>= 1) sum += __shfl_down(sum, off);
    if (lane == 0) sconv[wid] = (sum * MOD_SCALE + mod_b[i]) * CONV_SCALE;
}

// ---------------- K1: zero the 1-px border of padded xs2p [8][66][66][512] bf16
__global__ void k_zero_border(unsigned short* __restrict__ xs2p) {
    int b = blockIdx.y;
    int p = blockIdx.x * 4 + (threadIdx.x >> 6);   // 0..259
    int lane = threadIdx.x & 63;
    int h, w;
    if (p < 66)       { h = 0;       w = p; }
    else if (p < 132) { h = 65;      w = p - 66; }
    else if (p < 196) { h = p - 131; w = 0; }      // rows 1..64
    else              { h = p - 195; w = 65; }
    int4 z = {0, 0, 0, 0};
    *(int4*)&xs2p[((size_t)(b * 66 + h) * 66 + w) * 512 + lane * 8] = z;
}

// ---------------- K2: xs2p[b][h+1][w+1][i] = bf16(input[b][i][h][w] * sconv[b][i])
__global__ void k_scale_input(const float* __restrict__ input, const float* __restrict__ sconv,
                              unsigned short* __restrict__ xs2p) {
    int i0 = blockIdx.x * 32;
    int h  = blockIdx.y;
    int b  = blockIdx.z;
    __shared__ unsigned short lds[64][40];   // [w][ii], padded row
    #pragma unroll
    for (int r = 0; r < 8; ++r) {
        int ii = r * 4 + (threadIdx.x >> 6);
        int w  = threadIdx.x & 63;
        float v = input[(((size_t)b * CIN + i0 + ii) * HH + h) * WW + w];
        float s = sconv[b * CIN + i0 + ii];
        lds[w][ii] = f32_to_bf16_rne(v * s);
    }
    __syncthreads();
    int w = threadIdx.x >> 2, q = threadIdx.x & 3;
    int4 val = *(const int4*)&lds[w][q * 8];
    *(int4*)&xs2p[((size_t)(b * 66 + h + 1) * 66 + (w + 1)) * 512 + i0 + q * 8] = val;
}

// ---------------- K3: w3 ts-linear weights. ts = c*9+tap.
// byte addr = ts*32768 + h*16384 + (g*256 + ol)*16 ; elem += i&7 ; oc = h*256+ol
__global__ void k_weight(const float* __restrict__ weight, unsigned short* __restrict__ w3) {
    int t = blockIdx.x * 256 + threadIdx.x;   // 0 .. 512*512-1 : o*512 + i
    int o = t >> 9, i = t & 511;
    int c = i >> 5, g = (i >> 3) & 3, il = i & 7;
    int h = o >> 8, ol = o & 255;
    const float* src = weight + ((size_t)o * CIN + i) * 9;
    #pragma unroll
    for (int p = 0; p < 9; ++p) {
        size_t gran = ((size_t)(c * 9 + p) * 2 + h) * 1024 + g * 256 + ol;
        w3[gran * 8 + il] = f32_to_bf16_rne(src[p]);
    }
}

// ---------------- K4: main conv. 256 thr / 4 waves; TWO independent blocks per CU.
// Block tile 128 OC x (4 rows x 64 px); wave tile 64 oc x 128 px (mt2 x nt4).
// W: global->VGPR (ts-linear w3, E/O dbuf; compiler tracks reg deps).
// X: LDS 2x32KB, staged 8 GLD/thread over taps 0..3; vmcnt(0)+barrier per chunk.
// R10 bug fixed: staging pointers sx0/sx1 must be PRE-ADVANCED to chunk 1 after
// the prologue (R9/R10 re-staged the current chunk -> off-by-one channel pairing).
#define GLD(srcp, ldsbyte)                                                        \
    __builtin_amdgcn_global_load_lds(                                             \
        (const __attribute__((address_space(1))) unsigned int*)(srcp),            \
        (__attribute__((address_space(3))) unsigned int*)(smb + (ldsbyte)),       \
        16, 0, 0)

#define TAP(t, DOX, DOW, ENDCH, C, N) {                                           \
    if (DOW) {                                                                    \
        aW##N[0][0] = *(const bf16x8*)(pA);                                       \
        aW##N[1][0] = *(const bf16x8*)(pA + 512);                                 \
        aW##N[0][1] = *(const bf16x8*)(pA + 8192);                                \
        aW##N[1][1] = *(const bf16x8*)(pA + 8704);                                \
        pA += 32768;                                                              \
    }                                                                             \
    if ((DOX) && (t) < 4) {                                                       \
        GLD(sx0 + (t) * 16, xwr + (t) * 8192 + wdst0);                            \
        GLD(sx1 + (t) * 16, xwr + (t) * 8192 + wdst1);                            \
    }                                                                             \
    {   const int kh_ = (t) / 3, kw_ = (t) % 3;                                   \
        const char* xb = smb + xrd + boff + (kh_ * 66 + kw_) * 16;                \
        bfr[0][0] = *(const bf16x8*)(xb);                                         \
        bfr[1][0] = *(const bf16x8*)(xb + 512);                                   \
        bfr[2][0] = *(const bf16x8*)(xb + 1056);                                  \
        bfr[3][0] = *(const bf16x8*)(xb + 1568);                                  \
        bfr[0][1] = *(const bf16x8*)(xb + 16384);                                 \
        bfr[1][1] = *(const bf16x8*)(xb + 16896);                                 \
        bfr[2][1] = *(const bf16x8*)(xb + 17440);                                 \
        bfr[3][1] = *(const bf16x8*)(xb + 17952);                                 \
    }                                                                             \
    __builtin_amdgcn_s_setprio(1);                                                \
    _Pragma("unroll") for (int h = 0; h < 2; ++h)                                 \
      _Pragma("unroll") for (int mt = 0; mt < 2; ++mt)                            \
        _Pragma("unroll") for (int nt = 0; nt < 4; ++nt)                          \
            acc[mt][nt] = __builtin_amdgcn_mfma_f32_32x32x16_bf16(                \
                aW##C[mt][h], bfr[nt][h], acc[mt][nt], 0, 0, 0);                  \
    __builtin_amdgcn_s_setprio(0);                                                \
    if (ENDCH) { asm volatile("s_waitcnt vmcnt(0)" ::: "memory");                 \
                 __builtin_amdgcn_s_barrier();                                    \
                 xrd ^= 32768; sx0 += 64; sx1 += 64; }                            \
}

// full chunk starting on E parity (chunks 0,2,..,14): stages X(c+1), prefetches W
#define CHUNKE_FULL {                                                             \
    const int xwr = xrd ^ 32768;                                                  \
    TAP(0, 1, 1, 0, E, O) TAP(1, 1, 1, 0, O, E) TAP(2, 1, 1, 0, E, O)             \
    TAP(3, 1, 1, 0, O, E) TAP(4, 0, 1, 0, E, O) TAP(5, 0, 1, 0, O, E)             \
    TAP(6, 0, 1, 0, E, O) TAP(7, 0, 1, 0, O, E) TAP(8, 0, 1, 1, E, O) }
// full chunk starting on O parity (chunks 1,3,..,13)
#define CHUNKO_FULL {                                                             \
    const int xwr = xrd ^ 32768;                                                  \
    TAP(0, 1, 1, 0, O, E) TAP(1, 1, 1, 0, E, O) TAP(2, 1, 1, 0, O, E)             \
    TAP(3, 1, 1, 0, E, O) TAP(4, 0, 1, 0, O, E) TAP(5, 0, 1, 0, E, O)             \
    TAP(6, 0, 1, 0, O, E) TAP(7, 0, 1, 0, E, O) TAP(8, 0, 1, 1, O, E) }
// tail chunk 15 (starts O): no X stage, last W load at tap7 (ts143), no barrier
#define CHUNKO_TAIL {                                                             \
    const int xwr = 0; (void)xwr;                                                 \
    TAP(0, 0, 1, 0, O, E) TAP(1, 0, 1, 0, E, O) TAP(2, 0, 1, 0, O, E)             \
    TAP(3, 0, 1, 0, E, O) TAP(4, 0, 1, 0, O, E) TAP(5, 0, 1, 0, E, O)             \
    TAP(6, 0, 1, 0, O, E) TAP(7, 0, 1, 0, E, O) TAP(8, 0, 0, 0, O, E) }

__global__ __launch_bounds__(256, 2)
void k_conv(const unsigned short* __restrict__ xs2p, const unsigned short* __restrict__ w3,
            float* __restrict__ out) {
    __shared__ unsigned short smem[32768];   // 65536 bytes: X double buffer only
    char* smb = (char*)smem;

    const int tid  = threadIdx.x;
    const int wid  = tid >> 6, lane = tid & 63;
    const int wm4  = wid >> 1, wr2  = wid & 1;    // oc half (of 128) / row pair
    const int l31  = lane & 31, l5  = lane >> 5;
    const int y0   = blockIdx.x * 4;              // 16 y-groups (fast dim -> XCD spread)
    const int ocq  = blockIdx.y;                  // 0..3 -> oc0 = ocq*128 (siblings same XCD)
    const int b    = blockIdx.z;

    // X staging sources: pixel slots tid and tid+256 of the 396-px halo tile
    const char* sx0 = (const char*)xs2p;
    const char* sx1 = (const char*)xs2p;
    {
        int p0 = tid,      r0 = p0 / 66, c0 = p0 - r0 * 66;
        int p1 = tid + 256;
        sx0 += ((size_t)(b * 66 + y0 + r0) * 66 + c0) * 1024;       // 1KB per pixel
        if (p1 < 396) {
            int r1 = p1 / 66, c1 = p1 - r1 * 66;
            sx1 += ((size_t)(b * 66 + y0 + r1) * 66 + c1) * 1024;
        }
    }
    const int wdst0 = tid * 16;
    const int wdst1 = (tid + 256) * 16;

    // per-lane W source: ts*32768 + (ocq>>1)*16384 + (l5*256 + (ocq&1)*128 + wm4*64 + l31)*16
    const char* pA = (const char*)w3 + (size_t)(ocq >> 1) * 16384
                   + ((size_t)(l5 * 256 + (ocq & 1) * 128 + wm4 * 64 + l31)) * 16;

    // ---- prologue: X(0) into buf0 (8 GLDs), W(ts0) into E regs
    GLD(sx0 +  0, 0 * 8192 + wdst0); GLD(sx1 +  0, 0 * 8192 + wdst1);
    GLD(sx0 + 16, 1 * 8192 + wdst0); GLD(sx1 + 16, 1 * 8192 + wdst1);
    GLD(sx0 + 32, 2 * 8192 + wdst0); GLD(sx1 + 32, 2 * 8192 + wdst1);
    GLD(sx0 + 48, 3 * 8192 + wdst0); GLD(sx1 + 48, 3 * 8192 + wdst1);
    sx0 += 64; sx1 += 64;   // FIX: in-loop staging targets chunk c+1 (R9/R10 off-by-one)
    bf16x8 aWE[2][2], aWO[2][2], bfr[4][2];
    aWE[0][0] = *(const bf16x8*)(pA);
    aWE[1][0] = *(const bf16x8*)(pA + 512);
    aWE[0][1] = *(const bf16x8*)(pA + 8192);
    aWE[1][1] = *(const bf16x8*)(pA + 8704);
    pA += 32768;                                  // -> W(ts1)
    asm volatile("s_waitcnt vmcnt(0)" ::: "memory");  // everything landed
    __builtin_amdgcn_s_barrier();

    f32x16 acc[2][4];
    #pragma unroll
    for (int mt = 0; mt < 2; ++mt)
        #pragma unroll
        for (int nt = 0; nt < 4; ++nt)
            acc[mt][nt] = (f32x16)(0.f);

    // X frag base: plane l5, row pair 2*wr2, px l31
    const int boff = l5 * 8192 + (wr2 * 2 * 66 + l31) * 16;

    int xrd = 0;                                  // X read buffer byte offset

    for (int c2 = 0; c2 < 7; ++c2) {
        CHUNKE_FULL   // even chunk
        CHUNKO_FULL   // odd chunk
    }
    CHUNKE_FULL       // chunk 14 (stages X(15))
    CHUNKO_TAIL       // chunk 15

    // ---- epilogue: 32x32 C/D: col(px)=lane&31, row(oc)=(r&3)+8*(r>>2)+4*l5
    #pragma unroll
    for (int mt = 0; mt < 2; ++mt)
        #pragma unroll
        for (int nt = 0; nt < 4; ++nt) {
            const int y  = y0 + wr2 * 2 + (nt >> 1);
            const int px = (nt & 1) * 32 + l31;
            #pragma unroll
            for (int r = 0; r < 16; ++r) {
                int row = (r & 3) + 8 * (r >> 2) + 4 * l5;
                int oc  = ocq * 128 + wm4 * 64 + mt * 32 + row;
                out[((size_t)(b * COUT + oc) << 12) + y * 64 + px] = acc[mt][nt][r];
            }
        }
}

extern "C" void kernel_launch(void* const* d_in, const int* in_sizes, int n_in,
                              void* d_out, int out_size, void* d_ws, size_t ws_size,
                              hipStream_t stream) {
    const float* input  = (const float*)d_in[0];
    const float* style  = (const float*)d_in[1];
    const float* weight = (const float*)d_in[2];
    const float* mod_w  = (const float*)d_in[3];
    const float* mod_b  = (const float*)d_in[4];
    float* out = (float*)d_out;

    const size_t xs2p_bytes = (size_t)BB * 66 * 66 * 512 * 2;   // 35,684,352
    const size_t w3_bytes   = (size_t)144 * 2 * 1024 * 8 * 2;   // 4,718,592
    const size_t need = 16384 + xs2p_bytes + w3_bytes;
    if (ws_size < need) return;   // leave output poisoned -> clear failure

    float*          sconv = (float*)d_ws;
    unsigned short* xs2p  = (unsigned short*)((char*)d_ws + 16384);
    unsigned short* w3    = (unsigned short*)((char*)d_ws + 16384 + xs2p_bytes);

    hipLaunchKernelGGL(k_style,       dim3(1024),      dim3(256), 0, stream, style, mod_w, mod_b, sconv);
    hipLaunchKernelGGL(k_weight,      dim3(1024),      dim3(256), 0, stream, weight, w3);
    hipLaunchKernelGGL(k_zero_border, dim3(65, 8),     dim3(256), 0, stream, xs2p);
    hipLaunchKernelGGL(k_scale_input, dim3(16, 64, 8), dim3(256), 0, stream, input, sconv, xs2p);
    hipLaunchKernelGGL(k_conv,        dim3(16, 4, 8),  dim3(256), 0, stream, xs2p, w3, out);
}

// Round 12
// 176.622 us; speedup vs baseline: 1.0293x; 1.0293x over previous
//
#include <hip/hip_runtime.h>
#include <hip/hip_bf16.h>

#define BB   8
#define CIN  512
#define COUT 512
#define ZD   512
#define HH   64
#define WW   64

#define MOD_SCALE  0.04419417382415922f    // 1/sqrt(512)
#define CONV_SCALE 0.014731391274719742f   // 1/sqrt(512*9)

typedef __bf16 bf16x8 __attribute__((ext_vector_type(8)));
typedef float  f32x16 __attribute__((ext_vector_type(16)));

static __device__ __forceinline__ unsigned short f32_to_bf16_rne(float f) {
    unsigned int u = __float_as_uint(f);
    u = (u + 0x7FFFu + ((u >> 16) & 1u)) >> 16;
    return (unsigned short)u;
}

// ---------------- K0: sconv[b][i] = (style[b]·mod_w[i]*MOD_SCALE + mod_b[i]) * CONV_SCALE
__global__ void k_style(const float* __restrict__ style, const float* __restrict__ mod_w,
                        const float* __restrict__ mod_b, float* __restrict__ sconv) {
    int wid  = blockIdx.x * 4 + (threadIdx.x >> 6);   // 0..4095 = b*512+i
    int lane = threadIdx.x & 63;
    int b = wid >> 9;
    int i = wid & 511;
    const float4* st = (const float4*)(style + (size_t)b * ZD);
    const float4* mw = (const float4*)(mod_w + (size_t)i * ZD);
    float4 a0 = st[lane],      b0 = mw[lane];
    float4 a1 = st[lane + 64], b1 = mw[lane + 64];
    float sum = a0.x*b0.x + a0.y*b0.y + a0.z*b0.z + a0.w*b0.w
              + a1.x*b1.x + a1.y*b1.y + a1.z*b1.z + a1.w*b1.w;
    #pragma unroll
    for (int off = 32; off > 0; off >>= 1) sum += __shfl_down(sum, off);
    if (lane == 0) sconv[wid] = (sum * MOD_SCALE + mod_b[i]) * CONV_SCALE;
}

// ---------------- K1: zero the 1-px border of padded xs2p [8][66][66][512] bf16
__global__ void k_zero_border(unsigned short* __restrict__ xs2p) {
    int b = blockIdx.y;
    int p = blockIdx.x * 4 + (threadIdx.x >> 6);   // 0..259
    int lane = threadIdx.x & 63;
    int h, w;
    if (p < 66)       { h = 0;       w = p; }
    else if (p < 132) { h = 65;      w = p - 66; }
    else if (p < 196) { h = p - 131; w = 0; }      // rows 1..64
    else              { h = p - 195; w = 65; }
    int4 z = {0, 0, 0, 0};
    *(int4*)&xs2p[((size_t)(b * 66 + h) * 66 + w) * 512 + lane * 8] = z;
}

// ---------------- K2: xs2p[b][h+1][w+1][i] = bf16(input[b][i][h][w] * sconv[b][i])
__global__ void k_scale_input(const float* __restrict__ input, const float* __restrict__ sconv,
                              unsigned short* __restrict__ xs2p) {
    int i0 = blockIdx.x * 32;
    int h  = blockIdx.y;
    int b  = blockIdx.z;
    __shared__ unsigned short lds[64][40];   // [w][ii], padded row
    #pragma unroll
    for (int r = 0; r < 8; ++r) {
        int ii = r * 4 + (threadIdx.x >> 6);
        int w  = threadIdx.x & 63;
        float v = input[(((size_t)b * CIN + i0 + ii) * HH + h) * WW + w];
        float s = sconv[b * CIN + i0 + ii];
        lds[w][ii] = f32_to_bf16_rne(v * s);
    }
    __syncthreads();
    int w = threadIdx.x >> 2, q = threadIdx.x & 3;
    int4 val = *(const int4*)&lds[w][q * 8];
    *(int4*)&xs2p[((size_t)(b * 66 + h + 1) * 66 + (w + 1)) * 512 + i0 + q * 8] = val;
}

// ---------------- K3: w3 ts-linear weights. ts = c*9+tap.
// byte addr = ts*32768 + h*16384 + (g*256 + ol)*16 ; elem += i&7 ; oc = h*256+ol
__global__ void k_weight(const float* __restrict__ weight, unsigned short* __restrict__ w3) {
    int t = blockIdx.x * 256 + threadIdx.x;   // 0 .. 512*512-1 : o*512 + i
    int o = t >> 9, i = t & 511;
    int c = i >> 5, g = (i >> 3) & 3, il = i & 7;
    int h = o >> 8, ol = o & 255;
    const float* src = weight + ((size_t)o * CIN + i) * 9;
    #pragma unroll
    for (int p = 0; p < 9; ++p) {
        size_t gran = ((size_t)(c * 9 + p) * 2 + h) * 1024 + g * 256 + ol;
        w3[gran * 8 + il] = f32_to_bf16_rne(src[p]);
    }
}

// ---------------- K4: main conv. 512 thr / 8 waves; LDS 81920 B -> TWO blocks/CU
// (16 waves/CU = 4/SIMD). Block tile 128 oc x 4 rows x 64 px; wave 64oc x 64px
// (8 MFMA 32x32x16 + 8 ds_read_b128 per ts). W: LDS 3x8KB lead-2 ring via GLD.
// X: LDS 2x28672 (4 planes x 448 slots x 16B), staged taps 0..3 by waves 0..6.
// One barrier/ts; counted vmcnt (wave-uniform split: X-staging waves vs wave 7).
#define GLD(srcp, ldsbyte)                                                        \
    __builtin_amdgcn_global_load_lds(                                             \
        (const __attribute__((address_space(1))) unsigned int*)(srcp),            \
        (__attribute__((address_space(3))) unsigned int*)(smb + (ldsbyte)),       \
        16, 0, 0)

#define TAP(t, VMA, VMAW, DOX, DOW) {                                             \
    const int wwr_ = (wrd >= 8192) ? (wrd - 8192) : 16384;                        \
    if ((DOX) && (t) < 4 && tid < 448)                                            \
        GLD(sx + (t) * 16, (xrd ^ 45056) + (t) * 7168 + wdst);                    \
    if (DOW) { GLD(pW, wwr_ + wdst); pW += 32768; }                               \
    {   const int ko_ = (((t) / 3) * 66 + ((t) % 3)) * 16;                        \
        const char* wb = smb + wrd + aoff;                                        \
        const char* xb = smb + xrd + boff + ko_;                                  \
        afr[0][0] = *(const bf16x8*)(wb);                                         \
        afr[0][1] = *(const bf16x8*)(wb + 512);                                   \
        afr[1][0] = *(const bf16x8*)(wb + 4096);                                  \
        afr[1][1] = *(const bf16x8*)(wb + 4608);                                  \
        bfr[0][0] = *(const bf16x8*)(xb);                                         \
        bfr[0][1] = *(const bf16x8*)(xb + 512);                                   \
        bfr[1][0] = *(const bf16x8*)(xb + 14336);                                 \
        bfr[1][1] = *(const bf16x8*)(xb + 14848);                                 \
    }                                                                             \
    __builtin_amdgcn_s_setprio(1);                                                \
    _Pragma("unroll") for (int h = 0; h < 2; ++h)                                 \
      _Pragma("unroll") for (int mt = 0; mt < 2; ++mt)                            \
        _Pragma("unroll") for (int nt = 0; nt < 2; ++nt)                          \
            acc[mt][nt] = __builtin_amdgcn_mfma_f32_32x32x16_bf16(                \
                afr[h][mt], bfr[h][nt], acc[mt][nt], 0, 0, 0);                    \
    __builtin_amdgcn_s_setprio(0);                                                \
    if (tid < 448) { asm volatile("s_waitcnt vmcnt(" #VMA ")" ::: "memory"); }    \
    else           { asm volatile("s_waitcnt vmcnt(" #VMAW ")" ::: "memory"); }   \
    __builtin_amdgcn_s_barrier();                                                 \
    wrd = (wrd == 16384) ? 0 : (wrd + 8192);                                      \
}

// full chunks 0..14: stage X(c+1) (taps 0-3), W lead-2 every tap
#define CHUNK_FULL {                                                              \
    TAP(0, 2, 1, 1, 1) TAP(1, 2, 1, 1, 1) TAP(2, 2, 1, 1, 1) TAP(3, 2, 1, 1, 1)  \
    TAP(4, 1, 1, 0, 1) TAP(5, 1, 1, 0, 1) TAP(6, 1, 1, 0, 1) TAP(7, 1, 1, 0, 1)  \
    TAP(8, 1, 1, 0, 1)                                                            \
    xrd ^= 45056; sx += 64; }
// tail chunk 15: no X; last W (ts143) issued at tap 6
#define CHUNK_TAIL {                                                              \
    TAP(0, 1, 1, 0, 1) TAP(1, 1, 1, 0, 1) TAP(2, 1, 1, 0, 1) TAP(3, 1, 1, 0, 1)  \
    TAP(4, 1, 1, 0, 1) TAP(5, 1, 1, 0, 1) TAP(6, 1, 1, 0, 1)                     \
    TAP(7, 0, 0, 0, 0) TAP(8, 0, 0, 0, 0) }

__global__ __launch_bounds__(512, 4)
void k_conv(const unsigned short* __restrict__ xs2p, const unsigned short* __restrict__ w3,
            float* __restrict__ out) {
    __shared__ unsigned short smem[40960];   // 81920 B: W 3x8192 @0, X 2x28672 @24576
    char* smb = (char*)smem;

    const int tid = threadIdx.x;
    const int wid = tid >> 6, lane = tid & 63;
    const int wm  = wid >> 2, wr = wid & 3;       // oc half / row
    const int l31 = lane & 31, l5 = lane >> 5;
    const int y0  = blockIdx.x * 4;
    const int ocq = blockIdx.y;                   // 0..3 -> oc0 = ocq*128
    const int b   = blockIdx.z;

    // X staging source: slot = tid (valid < 396; 396..447 clamped to base, harmless)
    const char* sx = (const char*)xs2p;
    {
        int slot = tid, r0 = slot / 66, c0 = slot - r0 * 66;
        if (slot < 396)
            sx += ((size_t)(b * 66 + y0 + r0) * 66 + c0) * 1024;   // 1KB per pixel
    }
    const int wdst = tid * 16;

    // per-thread W source: granule g = tid>>7, ol = (ocq&1)*128 + (tid&127)
    const char* pW = (const char*)w3 + (size_t)(ocq >> 1) * 16384
                   + ((size_t)((tid >> 7) * 256 + (ocq & 1) * 128 + (tid & 127))) * 16;

    // ---- prologue: X(0) planes 0-3, W(ts0)->buf0, W(ts1)->buf1
    if (tid < 448) {
        GLD(sx +  0, 24576 + 0 * 7168 + wdst);
        GLD(sx + 16, 24576 + 1 * 7168 + wdst);
        GLD(sx + 32, 24576 + 2 * 7168 + wdst);
        GLD(sx + 48, 24576 + 3 * 7168 + wdst);
    }
    GLD(pW,         0    + wdst);
    GLD(pW + 32768, 8192 + wdst);
    pW += 2 * 32768;                              // -> W(ts2)
    sx += 64;                                     // in-loop staging targets chunk c+1
    asm volatile("s_waitcnt vmcnt(1)" ::: "memory");  // X(0)+W0 done; W1 in flight
    __builtin_amdgcn_s_barrier();

    f32x16 acc[2][2];
    #pragma unroll
    for (int mt = 0; mt < 2; ++mt)
        #pragma unroll
        for (int nt = 0; nt < 2; ++nt)
            acc[mt][nt] = (f32x16)(0.f);

    const int aoff = l5 * 2048 + (wm * 64 + l31) * 16;   // W frag base (bytes)
    const int boff = l5 * 7168 + (wr * 66 + l31) * 16;   // X frag base (bytes)

    bf16x8 afr[2][2], bfr[2][2];
    int wrd = 0;          // W read buf {0,8192,16384}
    int xrd = 24576;      // X read buf {24576,53248}

    for (int c = 0; c < 15; ++c) { CHUNK_FULL }
    CHUNK_TAIL

    // ---- epilogue: 32x32 C/D: col(px)=lane&31, row(oc)=(r&3)+8*(r>>2)+4*l5
    const int y = y0 + wr;
    #pragma unroll
    for (int mt = 0; mt < 2; ++mt)
        #pragma unroll
        for (int nt = 0; nt < 2; ++nt) {
            const int px = nt * 32 + l31;
            #pragma unroll
            for (int r = 0; r < 16; ++r) {
                int row = (r & 3) + 8 * (r >> 2) + 4 * l5;
                int oc  = ocq * 128 + wm * 64 + mt * 32 + row;
                out[((size_t)(b * COUT + oc) << 12) + y * 64 + px] = acc[mt][nt][r];
            }
        }
}

extern "C" void kernel_launch(void* const* d_in, const int* in_sizes, int n_in,
                              void* d_out, int out_size, void* d_ws, size_t ws_size,
                              hipStream_t stream) {
    const float* input  = (const float*)d_in[0];
    const float* style  = (const float*)d_in[1];
    const float* weight = (const float*)d_in[2];
    const float* mod_w  = (const float*)d_in[3];
    const float* mod_b  = (const float*)d_in[4];
    float* out = (float*)d_out;

    const size_t xs2p_bytes = (size_t)BB * 66 * 66 * 512 * 2;   // 35,684,352
    const size_t w3_bytes   = (size_t)144 * 2 * 1024 * 8 * 2;   // 4,718,592
    const size_t need = 16384 + xs2p_bytes + w3_bytes;
    if (ws_size < need) return;   // leave output poisoned -> clear failure

    float*          sconv = (float*)d_ws;
    unsigned short* xs2p  = (unsigned short*)((char*)d_ws + 16384);
    unsigned short* w3    = (unsigned short*)((char*)d_ws + 16384 + xs2p_bytes);

    hipLaunchKernelGGL(k_style,       dim3(1024),      dim3(256), 0, stream, style, mod_w, mod_b, sconv);
    hipLaunchKernelGGL(k_weight,      dim3(1024),      dim3(256), 0, stream, weight, w3);
    hipLaunchKernelGGL(k_zero_border, dim3(65, 8),     dim3(256), 0, stream, xs2p);
    hipLaunchKernelGGL(k_scale_input, dim3(16, 64, 8), dim3(256), 0, stream, input, sconv, xs2p);
    hipLaunchKernelGGL(k_conv,        dim3(16, 4, 8),  dim3(512), 0, stream, xs2p, w3, out);
}